// Round 5
// baseline (322.513 us; speedup 1.0000x reference)
//
#include <hip/hip_runtime.h>
#include <hip/hip_bf16.h>

#define IN_DIM 256
#define OUT_DIM 256
#define CAP 64      // max degree; deg ~ Poisson(16), P(deg>=64) ~ 1e-19

typedef __attribute__((ext_vector_type(8))) short bf16x8;
typedef __attribute__((ext_vector_type(4))) float f32x4;

__device__ inline unsigned short bfbits(float x) {
    __hip_bfloat16 h = __float2bfloat16(x);
    return *(unsigned short*)&h;
}
__device__ inline float4 bf4_to_f4(ushort4 u) {
    float4 r;
    r.x = __uint_as_float((unsigned)u.x << 16);
    r.y = __uint_as_float((unsigned)u.y << 16);
    r.z = __uint_as_float((unsigned)u.z << 16);
    r.w = __uint_as_float((unsigned)u.w << 16);
    return r;
}

// ---------------- prep: [0,FB) feat->bf16 | [FB,FB+256) W-transpose | rest: zero cursor ----------------

__global__ void prep_kernel(const float* __restrict__ feat, const float* __restrict__ W,
                            unsigned short* __restrict__ featb, unsigned short* __restrict__ Wt,
                            int* __restrict__ cursor, int nfeat, int FB, int ncur) {
    int b = blockIdx.x, tid = threadIdx.x;
    if (b < FB) {
        int i = (b * 256 + tid) * 4;
        if (i < nfeat) {
            float4 v = *(const float4*)(feat + i);
            ushort4 u;
            u.x = bfbits(v.x); u.y = bfbits(v.y); u.z = bfbits(v.z); u.w = bfbits(v.w);
            *(ushort4*)(featb + i) = u;
        }
    } else if (b < FB + OUT_DIM) {
        int n = b - FB;
        Wt[n * IN_DIM + tid] = bfbits(W[tid * OUT_DIM + n]);   // Wt[n][k], bf16
    } else {
        int i = ((b - FB - OUT_DIM) * 256 + tid) * 4;
        if (i < ncur) *(int4*)(cursor + i) = make_int4(0, 0, 0, 0);
    }
}

// ---------------- bucket build: padded cursor (1 counter per 64B line), ushort payload ----------------

__global__ void bucket_kernel(const int* __restrict__ src, const int* __restrict__ dst,
                              int* __restrict__ cursor, unsigned short* __restrict__ bucket, int E) {
    int e = blockIdx.x * 256 + threadIdx.x;
    if (e < E) {
        int d = dst[e];
        int pos = atomicAdd(&cursor[d << 4], 1);
        if (pos < CAP) bucket[d * CAP + pos] = (unsigned short)src[e];
    }
}

// ---------------- fused aggregate + GEMM: barrier-free ----------------
// Block = 4 waves x 16 nodes. Each wave gathers its 16 nodes' bf16 rows into its PRIVATE LDS
// region (no cross-wave sharing -> zero __syncthreads), then MFMAs its own rows vs Wt.
// B-fragments load straight from global Wt (128 KB, L2-hot) - no B staging, no barriers.

__global__ __launch_bounds__(256, 3) void agg_gemm(const unsigned short* __restrict__ featb,
                                                   const unsigned short* __restrict__ bucket,
                                                   const int* __restrict__ cursor,
                                                   const unsigned short* __restrict__ Wt,
                                                   float* __restrict__ C, int N) {
    __shared__ __align__(16) unsigned short sA[4][16][264];   // pitch 264: 16B-aligned rows, spread banks
    int tid = threadIdx.x;
    int w = tid >> 6, lane = tid & 63;
    int base = blockIdx.x * 64 + w * 16;

    // ---- phase 1: gather-aggregate 16 nodes (lane = 4 columns, 4-deep unrolled gather) ----
    for (int i = 0; i < 16; ++i) {
        int node = base + i;
        if (node >= N) break;
        int cnt = min(cursor[node << 4], CAP);
        const unsigned short* bp = bucket + node * CAP;
        float4 a0 = make_float4(0.f, 0.f, 0.f, 0.f), a1 = a0, a2 = a0, a3 = a0;
        int e = 0;
        for (; e + 4 <= cnt; e += 4) {
            int s0 = bp[e], s1 = bp[e + 1], s2 = bp[e + 2], s3 = bp[e + 3];
            float4 v0 = bf4_to_f4(((const ushort4*)(featb + (size_t)s0 * IN_DIM))[lane]);
            float4 v1 = bf4_to_f4(((const ushort4*)(featb + (size_t)s1 * IN_DIM))[lane]);
            float4 v2 = bf4_to_f4(((const ushort4*)(featb + (size_t)s2 * IN_DIM))[lane]);
            float4 v3 = bf4_to_f4(((const ushort4*)(featb + (size_t)s3 * IN_DIM))[lane]);
            a0.x += v0.x; a0.y += v0.y; a0.z += v0.z; a0.w += v0.w;
            a1.x += v1.x; a1.y += v1.y; a1.z += v1.z; a1.w += v1.w;
            a2.x += v2.x; a2.y += v2.y; a2.z += v2.z; a2.w += v2.w;
            a3.x += v3.x; a3.y += v3.y; a3.z += v3.z; a3.w += v3.w;
        }
        for (; e < cnt; ++e) {
            float4 v = bf4_to_f4(((const ushort4*)(featb + (size_t)bp[e] * IN_DIM))[lane]);
            a0.x += v.x; a0.y += v.y; a0.z += v.z; a0.w += v.w;
        }
        a0.x += a1.x + a2.x + a3.x;
        a0.y += a1.y + a2.y + a3.y;
        a0.z += a1.z + a2.z + a3.z;
        a0.w += a1.w + a2.w + a3.w;
        ushort4 o;
        o.x = bfbits(a0.x); o.y = bfbits(a0.y); o.z = bfbits(a0.z); o.w = bfbits(a0.w);
        *(ushort4*)&sA[w][i][lane * 4] = o;    // 8B/lane, 2 lanes/bank = free
    }

    // ---- phase 2: per-wave GEMM. m-tile = this wave's 16 nodes, all 256 out cols ----
    // (compiler inserts the lgkmcnt waits for our own LDS writes; no cross-wave deps exist)
    int m16 = lane & 15, quad = lane >> 4;
    f32x4 acc[16] = {};
    #pragma unroll
    for (int k0 = 0; k0 < IN_DIM; k0 += 32) {
        bf16x8 af = *(const bf16x8*)&sA[w][m16][k0 + quad * 8];   // A[m=m16][k=quad*8+j]
        #pragma unroll
        for (int nt = 0; nt < 16; ++nt) {
            bf16x8 bf = *(const bf16x8*)(Wt + (size_t)(nt * 16 + m16) * IN_DIM + k0 + quad * 8);
            acc[nt] = __builtin_amdgcn_mfma_f32_16x16x32_bf16(af, bf, acc[nt], 0, 0, 0);
        }
    }
    // epilogue: D row = quad*4+r, col = nt*16+m16 (verified layout from round-2/3 gemm)
    #pragma unroll
    for (int nt = 0; nt < 16; ++nt) {
        #pragma unroll
        for (int r = 0; r < 4; ++r) {
            int gr = base + quad * 4 + r;
            if (gr < N) C[(size_t)gr * OUT_DIM + nt * 16 + m16] = acc[nt][r];
        }
    }
}

// ---------------- launch ----------------

extern "C" void kernel_launch(void* const* d_in, const int* in_sizes, int n_in,
                              void* d_out, int out_size, void* d_ws, size_t ws_size,
                              hipStream_t stream) {
    const float* feature = (const float*)d_in[0];
    const float* weight  = (const float*)d_in[1];
    const int*   src     = (const int*)d_in[2];
    const int*   dst     = (const int*)d_in[3];
    float*       out     = (float*)d_out;

    int N = in_sizes[0] / IN_DIM;   // 50000 (fits ushort)
    int E = in_sizes[2];            // 800000
    int nfeat = N * IN_DIM;
    int ncur = N * 16;              // padded cursor ints

    // workspace layout (16B-aligned sections)
    char* ws = (char*)d_ws;
    unsigned short* featb = (unsigned short*)ws;                                // 25.6 MB
    unsigned short* Wt    = featb + (size_t)nfeat;                              // 128 KB
    int*            cursor = (int*)(ws + (size_t)nfeat * 2 + (size_t)IN_DIM * OUT_DIM * 2);  // 3.2 MB
    unsigned short* bucket = (unsigned short*)(cursor + ncur);                  // 6.4 MB

    int FB = (nfeat / 4 + 255) / 256;        // 12500 conversion blocks
    int CB = (ncur / 4 + 255) / 256;         // 782 cursor-clear blocks
    prep_kernel<<<FB + OUT_DIM + CB, 256, 0, stream>>>(feature, weight, featb, Wt, cursor,
                                                       nfeat, FB, ncur);
    bucket_kernel<<<(E + 255) / 256, 256, 0, stream>>>(src, dst, cursor, bucket, E);
    agg_gemm<<<(N + 63) / 64, 256, 0, stream>>>(featb, bucket, cursor, Wt, out, N);
}

// Round 6
// 250.417 us; speedup vs baseline: 1.2879x; 1.2879x over previous
//
#include <hip/hip_runtime.h>
#include <hip/hip_bf16.h>

#define IN_DIM 256
#define OUT_DIM 256
#define CAP 64      // max degree; deg ~ Poisson(16), P(deg>=64) ~ 1e-19

typedef __attribute__((ext_vector_type(8))) short bf16x8;
typedef __attribute__((ext_vector_type(4))) float f32x4;

__device__ inline unsigned short bfbits(float x) {
    __hip_bfloat16 h = __float2bfloat16(x);
    return *(unsigned short*)&h;
}
__device__ inline float4 bf4_to_f4(ushort4 u) {
    float4 r;
    r.x = __uint_as_float((unsigned)u.x << 16);
    r.y = __uint_as_float((unsigned)u.y << 16);
    r.z = __uint_as_float((unsigned)u.z << 16);
    r.w = __uint_as_float((unsigned)u.w << 16);
    return r;
}

// ---- fused prep: [0,EB) bucket build (padded cursor, ushort payload) | [EB,EB+FB) feat->bf16 | rest Wt ----

__global__ void fused_prep(const float* __restrict__ feat, const float* __restrict__ W,
                           const int* __restrict__ src, const int* __restrict__ dst,
                           unsigned short* __restrict__ featb, unsigned short* __restrict__ Wt,
                           int* __restrict__ cursor, unsigned short* __restrict__ bucket,
                           int E, int nfeat, int EB, int FB) {
    int b = blockIdx.x, tid = threadIdx.x;
    if (b < EB) {
        int e = b * 256 + tid;
        if (e < E) {
            int d = dst[e];
            int pos = atomicAdd(&cursor[d << 4], 1);   // 1 counter per 64B line
            if (pos < CAP) bucket[d * CAP + pos] = (unsigned short)src[e];
        }
    } else if (b < EB + FB) {
        int i = ((b - EB) * 256 + tid) * 4;
        if (i < nfeat) {
            float4 v = *(const float4*)(feat + i);
            ushort4 u;
            u.x = bfbits(v.x); u.y = bfbits(v.y); u.z = bfbits(v.z); u.w = bfbits(v.w);
            *(ushort4*)(featb + i) = u;
        }
    } else {
        int n = b - EB - FB;
        Wt[n * IN_DIM + tid] = bfbits(W[tid * OUT_DIM + n]);   // Wt[n][k] bf16
    }
}

// ---- fused aggregate + GEMM, parallelism-preserving ----
// 1024-thread block = 16 waves. Phase 1: wave w aggregates node base+w (identical to the proven
// round-3 loop: 1 wave per node, lane = 4 cols, 4-deep unrolled gather). Row -> LDS.
// One barrier. Phase 2: wave w computes the block's 16-row tile x cols [w*16,w*16+16):
// 8 MFMAs, A-frag from LDS, B-frag from L2-hot global Wt. No agg round-trip, no gemm kernel.

__global__ __launch_bounds__(1024) void agg_gemm(const unsigned short* __restrict__ featb,
                                                 const unsigned short* __restrict__ bucket,
                                                 const int* __restrict__ cursor,
                                                 const unsigned short* __restrict__ Wt,
                                                 float* __restrict__ C, int N) {
    __shared__ __align__(16) unsigned short sA[16][264];   // pitch = 33 x 16B: 2-way conflicts max
    int tid = threadIdx.x;
    int w = tid >> 6, lane = tid & 63;
    int base = blockIdx.x * 16;
    int node = base + w;

    // ---- phase 1: gather-aggregate (1 wave = 1 node) ----
    float4 a0 = make_float4(0.f, 0.f, 0.f, 0.f), a1 = a0, a2 = a0, a3 = a0;
    if (node < N) {
        int cnt = min(cursor[node << 4], CAP);
        const unsigned short* bp = bucket + node * CAP;
        int e = 0;
        for (; e + 4 <= cnt; e += 4) {
            int s0 = bp[e], s1 = bp[e + 1], s2 = bp[e + 2], s3 = bp[e + 3];
            float4 v0 = bf4_to_f4(((const ushort4*)(featb + (size_t)s0 * IN_DIM))[lane]);
            float4 v1 = bf4_to_f4(((const ushort4*)(featb + (size_t)s1 * IN_DIM))[lane]);
            float4 v2 = bf4_to_f4(((const ushort4*)(featb + (size_t)s2 * IN_DIM))[lane]);
            float4 v3 = bf4_to_f4(((const ushort4*)(featb + (size_t)s3 * IN_DIM))[lane]);
            a0.x += v0.x; a0.y += v0.y; a0.z += v0.z; a0.w += v0.w;
            a1.x += v1.x; a1.y += v1.y; a1.z += v1.z; a1.w += v1.w;
            a2.x += v2.x; a2.y += v2.y; a2.z += v2.z; a2.w += v2.w;
            a3.x += v3.x; a3.y += v3.y; a3.z += v3.z; a3.w += v3.w;
        }
        for (; e < cnt; ++e) {
            float4 v = bf4_to_f4(((const ushort4*)(featb + (size_t)bp[e] * IN_DIM))[lane]);
            a0.x += v.x; a0.y += v.y; a0.z += v.z; a0.w += v.w;
        }
    }
    a0.x += a1.x + a2.x + a3.x;
    a0.y += a1.y + a2.y + a3.y;
    a0.z += a1.z + a2.z + a3.z;
    a0.w += a1.w + a2.w + a3.w;
    ushort4 o;
    o.x = bfbits(a0.x); o.y = bfbits(a0.y); o.z = bfbits(a0.z); o.w = bfbits(a0.w);
    *(ushort4*)&sA[w][lane * 4] = o;      // 8 B/lane -> 2 lanes/bank = free
    __syncthreads();

    // ---- phase 2: wave w -> output cols [w*16, w*16+16) of this 16-row tile ----
    int m16 = lane & 15, quad = lane >> 4;
    f32x4 acc = {};
    #pragma unroll
    for (int k0 = 0; k0 < IN_DIM; k0 += 32) {
        bf16x8 af = *(const bf16x8*)&sA[m16][k0 + quad * 8];                         // A[m][k]
        bf16x8 bf = *(const bf16x8*)(Wt + (size_t)(w * 16 + m16) * IN_DIM + k0 + quad * 8);  // B[n][k]
        acc = __builtin_amdgcn_mfma_f32_16x16x32_bf16(af, bf, acc, 0, 0, 0);
    }
    #pragma unroll
    for (int r = 0; r < 4; ++r) {
        int gr = base + quad * 4 + r;     // D: row = quad*4+r, col = m16 (verified layout)
        if (gr < N) C[(size_t)gr * OUT_DIM + w * 16 + m16] = acc[r];
    }
}

// ---------------- launch ----------------

extern "C" void kernel_launch(void* const* d_in, const int* in_sizes, int n_in,
                              void* d_out, int out_size, void* d_ws, size_t ws_size,
                              hipStream_t stream) {
    const float* feature = (const float*)d_in[0];
    const float* weight  = (const float*)d_in[1];
    const int*   src     = (const int*)d_in[2];
    const int*   dst     = (const int*)d_in[3];
    float*       out     = (float*)d_out;

    int N = in_sizes[0] / IN_DIM;   // 50000 (fits ushort)
    int E = in_sizes[2];            // 800000
    int nfeat = N * IN_DIM;
    int ncur = N * 16;              // padded cursor ints (64 B per counter)

    // workspace layout (16B-aligned sections)
    char* ws = (char*)d_ws;
    unsigned short* featb  = (unsigned short*)ws;                                   // 25.6 MB
    unsigned short* Wt     = featb + (size_t)nfeat;                                 // 128 KB
    int*            cursor = (int*)(ws + (size_t)nfeat * 2 + (size_t)IN_DIM * OUT_DIM * 2);  // 3.2 MB
    unsigned short* bucket = (unsigned short*)(cursor + ncur);                      // 6.4 MB

    hipMemsetAsync(cursor, 0, (size_t)ncur * sizeof(int), stream);

    int EB = (E + 255) / 256;               // 3125 bucket blocks first (start atomics early)
    int FB = (nfeat / 4 + 255) / 256;       // 12500 conversion blocks
    fused_prep<<<EB + FB + OUT_DIM, 256, 0, stream>>>(feature, weight, src, dst,
                                                      featb, Wt, cursor, bucket, E, nfeat, EB, FB);

    agg_gemm<<<(N + 15) / 16, 1024, 0, stream>>>(featb, bucket, cursor, Wt, out, N);
}

// Round 7
// 219.790 us; speedup vs baseline: 1.4674x; 1.1393x over previous
//
#include <hip/hip_runtime.h>
#include <hip/hip_bf16.h>

#define IN_DIM 256
#define OUT_DIM 256
#define CAP 64      // max degree; deg ~ Poisson(16), P(deg>=64) ~ 1e-19

typedef __attribute__((ext_vector_type(8))) short bf16x8;
typedef __attribute__((ext_vector_type(4))) float f32x4;

__device__ inline unsigned short bfbits(float x) {
    __hip_bfloat16 h = __float2bfloat16(x);
    return *(unsigned short*)&h;
}
__device__ inline float4 bf4_to_f4(ushort4 u) {
    float4 r;
    r.x = __uint_as_float((unsigned)u.x << 16);
    r.y = __uint_as_float((unsigned)u.y << 16);
    r.z = __uint_as_float((unsigned)u.z << 16);
    r.w = __uint_as_float((unsigned)u.w << 16);
    return r;
}

// ---- prep: [0,FB) feat->bf16 | [FB,FB+256) W-transpose | rest cursor-zero. No atomics here. ----

__global__ void prep_kernel(const float* __restrict__ feat, const float* __restrict__ W,
                            unsigned short* __restrict__ featb, unsigned short* __restrict__ Wt,
                            int* __restrict__ cursor, int nfeat, int FB, int ncur) {
    int b = blockIdx.x, tid = threadIdx.x;
    if (b < FB) {
        int i = (b * 256 + tid) * 4;
        if (i < nfeat) {
            float4 v = *(const float4*)(feat + i);
            ushort4 u;
            u.x = bfbits(v.x); u.y = bfbits(v.y); u.z = bfbits(v.z); u.w = bfbits(v.w);
            *(ushort4*)(featb + i) = u;
        }
    } else if (b < FB + OUT_DIM) {
        int n = b - FB;
        Wt[n * IN_DIM + tid] = bfbits(W[tid * OUT_DIM + n]);   // Wt[n][k] bf16
    } else {
        int i = ((b - FB - OUT_DIM) * 256 + tid) * 4;
        if (i < ncur) *(int4*)(cursor + i) = make_int4(0, 0, 0, 0);
    }
}

// ---- bucket build STANDALONE, padded cursor (1 counter per 64B line): clean A/B vs r3's 59.2 µs ----

__global__ void bucket_kernel(const int* __restrict__ src, const int* __restrict__ dst,
                              int* __restrict__ cursor, unsigned short* __restrict__ bucket, int E) {
    int e = blockIdx.x * 256 + threadIdx.x;
    if (e < E) {
        int d = dst[e];
        int pos = atomicAdd(&cursor[d << 4], 1);
        if (pos < CAP) bucket[d * CAP + pos] = (unsigned short)src[e];
    }
}

// ---- aggregate: r3's proven 57.8 µs loop (1 wave = 1 node, lane = 4 cols, 4-deep unroll) ----

__global__ __launch_bounds__(256) void aggregate_bf16(const unsigned short* __restrict__ featb,
                                                      const unsigned short* __restrict__ bucket,
                                                      const int* __restrict__ cursor,
                                                      unsigned short* __restrict__ agg, int N) {
    int node = blockIdx.x * 4 + (threadIdx.x >> 6);
    int lane = threadIdx.x & 63;
    if (node >= N) return;
    int cnt = min(cursor[node << 4], CAP);
    const unsigned short* bp = bucket + node * CAP;
    float4 a0 = make_float4(0.f, 0.f, 0.f, 0.f), a1 = a0, a2 = a0, a3 = a0;
    int e = 0;
    for (; e + 4 <= cnt; e += 4) {
        int s0 = bp[e], s1 = bp[e + 1], s2 = bp[e + 2], s3 = bp[e + 3];
        float4 v0 = bf4_to_f4(((const ushort4*)(featb + (size_t)s0 * IN_DIM))[lane]);
        float4 v1 = bf4_to_f4(((const ushort4*)(featb + (size_t)s1 * IN_DIM))[lane]);
        float4 v2 = bf4_to_f4(((const ushort4*)(featb + (size_t)s2 * IN_DIM))[lane]);
        float4 v3 = bf4_to_f4(((const ushort4*)(featb + (size_t)s3 * IN_DIM))[lane]);
        a0.x += v0.x; a0.y += v0.y; a0.z += v0.z; a0.w += v0.w;
        a1.x += v1.x; a1.y += v1.y; a1.z += v1.z; a1.w += v1.w;
        a2.x += v2.x; a2.y += v2.y; a2.z += v2.z; a2.w += v2.w;
        a3.x += v3.x; a3.y += v3.y; a3.z += v3.z; a3.w += v3.w;
    }
    for (; e < cnt; ++e) {
        float4 v = bf4_to_f4(((const ushort4*)(featb + (size_t)bp[e] * IN_DIM))[lane]);
        a0.x += v.x; a0.y += v.y; a0.z += v.z; a0.w += v.w;
    }
    a0.x += a1.x + a2.x + a3.x;
    a0.y += a1.y + a2.y + a3.y;
    a0.z += a1.z + a2.z + a3.z;
    a0.w += a1.w + a2.w + a3.w;
    ushort4 o;
    o.x = bfbits(a0.x); o.y = bfbits(a0.y); o.z = bfbits(a0.z); o.w = bfbits(a0.w);
    ((ushort4*)(agg + (size_t)node * IN_DIM))[lane] = o;
}

// ---- GEMM: r2's verified MFMA kernel. C[M,256] = A[M,256]bf16 @ Wt, 64x128 tile ----

__global__ __launch_bounds__(256) void gemm_mfma(const unsigned short* __restrict__ A,
                                                 const unsigned short* __restrict__ Bt,
                                                 float* __restrict__ C, int M) {
    __shared__ unsigned short sA[64][40];
    __shared__ unsigned short sB[128][40];
    int tid = threadIdx.x;
    int wave = tid >> 6, lane = tid & 63;
    int m16 = lane & 15, quad = lane >> 4;
    int rb = blockIdx.y * 64, cb = blockIdx.x * 128;
    f32x4 acc[8] = {};

    for (int k0 = 0; k0 < IN_DIM; k0 += 32) {
        {
            int r = tid >> 2, g = tid & 3;
            int gr = rb + r;
            ulonglong2 v; v.x = 0; v.y = 0;
            if (gr < M) v = *(const ulonglong2*)(A + (size_t)gr * IN_DIM + k0 + g * 8);
            *(ulonglong2*)&sA[r][g * 8] = v;
        }
        #pragma unroll
        for (int t = 0; t < 2; ++t) {
            int f = tid + t * 256;
            int nrow = f >> 2, g = f & 3;
            *(ulonglong2*)&sB[nrow][g * 8] =
                *(const ulonglong2*)(Bt + (size_t)(cb + nrow) * IN_DIM + k0 + g * 8);
        }
        __syncthreads();
        bf16x8 afrag = *(const bf16x8*)&sA[wave * 16 + m16][quad * 8];
        #pragma unroll
        for (int nt = 0; nt < 8; ++nt) {
            bf16x8 bfrag = *(const bf16x8*)&sB[nt * 16 + m16][quad * 8];
            acc[nt] = __builtin_amdgcn_mfma_f32_16x16x32_bf16(afrag, bfrag, acc[nt], 0, 0, 0);
        }
        __syncthreads();
    }
    #pragma unroll
    for (int nt = 0; nt < 8; ++nt) {
        #pragma unroll
        for (int r = 0; r < 4; ++r) {
            int gr = rb + wave * 16 + quad * 4 + r;
            if (gr < M) C[(size_t)gr * OUT_DIM + cb + nt * 16 + m16] = acc[nt][r];
        }
    }
}

// ---------------- launch ----------------

extern "C" void kernel_launch(void* const* d_in, const int* in_sizes, int n_in,
                              void* d_out, int out_size, void* d_ws, size_t ws_size,
                              hipStream_t stream) {
    const float* feature = (const float*)d_in[0];
    const float* weight  = (const float*)d_in[1];
    const int*   src     = (const int*)d_in[2];
    const int*   dst     = (const int*)d_in[3];
    float*       out     = (float*)d_out;

    int N = in_sizes[0] / IN_DIM;   // 50000 (fits ushort)
    int E = in_sizes[2];            // 800000
    int nfeat = N * IN_DIM;
    int ncur = N * 16;              // padded cursor (64 B per counter)

    // workspace layout (16B-aligned sections)
    char* ws = (char*)d_ws;
    unsigned short* featb  = (unsigned short*)ws;                                   // 25.6 MB
    unsigned short* agg    = featb + (size_t)nfeat;                                 // 25.6 MB
    unsigned short* Wt     = agg + (size_t)nfeat;                                   // 128 KB
    int*            cursor = (int*)((char*)(Wt + IN_DIM * OUT_DIM));                // 3.2 MB
    unsigned short* bucket = (unsigned short*)(cursor + ncur);                      // 6.4 MB

    int FB = (nfeat / 4 + 255) / 256;        // 12500 conversion blocks
    int CB = (ncur / 4 + 255) / 256;         // 782 cursor-clear blocks
    prep_kernel<<<FB + OUT_DIM + CB, 256, 0, stream>>>(feature, weight, featb, Wt, cursor,
                                                       nfeat, FB, ncur);
    bucket_kernel<<<(E + 255) / 256, 256, 0, stream>>>(src, dst, cursor, bucket, E);
    aggregate_bf16<<<(N + 3) / 4, 256, 0, stream>>>(featb, bucket, cursor, agg, N);

    dim3 ggrid(OUT_DIM / 128, (N + 63) / 64);
    gemm_mfma<<<ggrid, 256, 0, stream>>>(agg, Wt, out, N);
}